// Round 2
// baseline (1756.716 us; speedup 1.0000x reference)
//
#include <hip/hip_runtime.h>
#include <stdint.h>

#define NN 20000
#define EE 640000
#define DDIM 128
#define D2 256
#define NLAY 3
#define BN_EPS 1e-5f

typedef short bf16x8 __attribute__((ext_vector_type(8)));
typedef float f32x4 __attribute__((ext_vector_type(4)));

__device__ __forceinline__ short f2bf(float f) {
    uint32_t u = __float_as_uint(f);
    u += 0x7fff + ((u >> 16) & 1);   // round-to-nearest-even
    return (short)(u >> 16);
}

// ---------------- embedding ----------------
__global__ __launch_bounds__(256) void k_embed(const int* __restrict__ tok,
                                               const float* __restrict__ emb,
                                               float* __restrict__ h) {
    int gid = blockIdx.x * 256 + threadIdx.x;
    int r = gid >> 5;
    int c4 = gid & 31;
    int t = tok[r];
    ((float4*)h)[gid] = ((const float4*)emb)[t * 32 + c4];
}

// ---------------- counting sort of edges by dst ----------------
__global__ __launch_bounds__(256) void k_hist(const int* __restrict__ ei, int* __restrict__ counts) {
    int e = blockIdx.x * 256 + threadIdx.x;
    atomicAdd(&counts[ei[EE + e]], 1);
}

__global__ __launch_bounds__(1024) void k_scan(const int* __restrict__ counts, int* __restrict__ cursor) {
    __shared__ int part[1024];
    int t = threadIdx.x;
    int base = t * 20;
    int s = 0;
    for (int i = 0; i < 20; i++) {
        int idx = base + i;
        if (idx < NN) s += counts[idx];
    }
    part[t] = s;
    __syncthreads();
    for (int off = 1; off < 1024; off <<= 1) {
        int v = (t >= off) ? part[t - off] : 0;
        __syncthreads();
        part[t] += v;
        __syncthreads();
    }
    int run = part[t] - s;
    for (int i = 0; i < 20; i++) {
        int idx = base + i;
        if (idx < NN) { cursor[idx] = run; run += counts[idx]; }
    }
}

__global__ __launch_bounds__(256) void k_scatter(const int* __restrict__ ei,
                                                 int* __restrict__ cursor,
                                                 int* __restrict__ perm) {
    int e = blockIdx.x * 256 + threadIdx.x;
    int d = ei[EE + e];
    int pos = atomicAdd(&cursor[d], 1);
    perm[pos] = e;
}

// ---------------- permute edge_attr into sorted order + bf16 ----------------
__global__ __launch_bounds__(256) void k_permute(const float* __restrict__ edge_attr,
                                                 const int* __restrict__ ei,
                                                 const int* __restrict__ perm,
                                                 short* __restrict__ ea_bf,
                                                 int* __restrict__ srcs,
                                                 int* __restrict__ dsts) {
    int gid = blockIdx.x * 256 + threadIdx.x;   // 0..EE*32-1
    int p = gid >> 5, c4 = gid & 31;
    int e = perm[p];
    float4 v = ((const float4*)edge_attr)[e * 32 + c4];
    short4 b;
    b.x = f2bf(v.x); b.y = f2bf(v.y); b.z = f2bf(v.z); b.w = f2bf(v.w);
    ((short4*)ea_bf)[gid] = b;
    if (c4 == 0) { srcs[p] = ei[e]; dsts[p] = ei[EE + e]; }
}

// ---------------- weight prep: transpose + fp32->bf16 ----------------
__global__ __launch_bounds__(256) void k_prepw(const float* __restrict__ src,
                                               short* __restrict__ dst,
                                               int K, int Nc, int total) {
    int gid = blockIdx.x * 256 + threadIdx.x;
    if (gid >= total) return;
    int per = K * Nc;
    int l = gid / per;
    int rem = gid - l * per;
    int k = rem / Nc;
    int n = rem - k * Nc;
    dst[(l * Nc + n) * K + k] = f2bf(src[gid]);
}

// ---------------- fused edge kernel (sorted contiguous bf16 path) ----------------
__global__ __launch_bounds__(256) void k_edge2(const short* __restrict__ ea_bf,
                                               const int* __restrict__ srcs,
                                               const int* __restrict__ dsts,
                                               const short* __restrict__ WtL,
                                               const float* __restrict__ ebL,
                                               const float* __restrict__ h,
                                               float* __restrict__ agg) {
    __shared__ __align__(16) short sW[128 * 136];    // 34816 B
    __shared__ __align__(16) float sOut[64 * 132];   // 33792 B
    __shared__ int sSrc[64], sDst[64];
    int tid = threadIdx.x;
    int tile = blockIdx.x;

    if (tid < 64) {
        sSrc[tid] = srcs[tile * 64 + tid];
        sDst[tid] = dsts[tile * 64 + tid];
    }
    // stage W (16384 bf16 = 4096 uint2)
    const uint2* wg = (const uint2*)WtL;
    #pragma unroll
    for (int i = 0; i < 16; i++) {
        int idx = tid + i * 256;
        uint2 v = wg[idx];
        int n = idx >> 5, k4 = (idx & 31) << 2;
        *(uint2*)&sW[n * 136 + k4] = v;
    }
    int lane = tid & 63, wv = tid >> 6;
    int l15 = lane & 15, quad = lane >> 4;
    int r0 = wv * 16;
    // A fragments straight from global (contiguous bf16 rows)
    const short* abase = ea_bf + ((size_t)(tile * 64 + r0 + l15)) * 128 + quad * 8;
    bf16x8 a[4];
    #pragma unroll
    for (int kt = 0; kt < 4; kt++) a[kt] = *(const bf16x8*)(abase + kt * 32);
    __syncthreads();   // sW ready

    f32x4 acc[8];
    #pragma unroll
    for (int i = 0; i < 8; i++) acc[i] = (f32x4){0.f, 0.f, 0.f, 0.f};
    #pragma unroll
    for (int kt = 0; kt < 4; kt++) {
        #pragma unroll
        for (int nt = 0; nt < 8; nt++) {
            bf16x8 b = *(const bf16x8*)&sW[(nt * 16 + l15) * 136 + kt * 32 + quad * 8];
            acc[nt] = __builtin_amdgcn_mfma_f32_16x16x32_bf16(a[kt], b, acc[nt], 0, 0, 0);
        }
    }
    #pragma unroll
    for (int nt = 0; nt < 8; nt++)
        #pragma unroll
        for (int reg = 0; reg < 4; reg++)
            sOut[(r0 + quad * 4 + reg) * 132 + nt * 16 + l15] = acc[nt][reg];
    __syncthreads();
    // fused bias + h-gather + relu + segmented reduce (2 halves in parallel)
    int c = tid & 127;
    int rbeg = (tid >> 7) * 32;
    float eb = ebL[c];
    float s = 0.f;
    int cur = sDst[rbeg];
    for (int r = rbeg; r < rbeg + 32; r++) {
        int d = sDst[r];
        if (d != cur) { atomicAdd(&agg[(size_t)cur * DDIM + c], s); s = 0.f; cur = d; }
        float v = sOut[r * 132 + c] + eb + h[(size_t)sSrc[r] * DDIM + c];
        s += fmaxf(v, 0.f);
    }
    atomicAdd(&agg[(size_t)cur * DDIM + c], s);
}

// ---------------- fallback edge kernel (gather, round-1 style) ----------------
__global__ __launch_bounds__(256) void k_edge_g(const float* __restrict__ edge_attr,
                                                const short* __restrict__ WtL,
                                                const float* __restrict__ ebL,
                                                const float* __restrict__ h,
                                                const int* __restrict__ ei,
                                                const int* __restrict__ perm,
                                                float* __restrict__ agg) {
    __shared__ __align__(16) short sW[128 * 136];
    __shared__ __align__(16) char sU[64 * 132 * 4];
    __shared__ int sSrc[64], sDst[64], sEdge[64];
    short* sA = (short*)sU;
    float* sOut = (float*)sU;
    int tid = threadIdx.x;
    int tile = blockIdx.x;
    if (tid < 64) {
        int e = perm[tile * 64 + tid];
        sEdge[tid] = e;
        sSrc[tid] = ei[e];
        sDst[tid] = ei[EE + e];
    }
    const uint2* wg = (const uint2*)WtL;
    #pragma unroll
    for (int i = 0; i < 16; i++) {
        int idx = tid + i * 256;
        uint2 v = wg[idx];
        int n = idx >> 5, k4 = (idx & 31) << 2;
        *(uint2*)&sW[n * 136 + k4] = v;
    }
    __syncthreads();
    #pragma unroll
    for (int i = 0; i < 8; i++) {
        int idx = tid + i * 256;
        int r = idx >> 5, c4 = idx & 31;
        float4 v = ((const float4*)edge_attr)[sEdge[r] * 32 + c4];
        short4 b;
        b.x = f2bf(v.x); b.y = f2bf(v.y); b.z = f2bf(v.z); b.w = f2bf(v.w);
        *(short4*)&sA[r * 136 + (c4 << 2)] = b;
    }
    __syncthreads();
    int lane = tid & 63, wv = tid >> 6;
    int l15 = lane & 15, quad = lane >> 4;
    int r0 = wv * 16;
    f32x4 acc[8];
    #pragma unroll
    for (int i = 0; i < 8; i++) acc[i] = (f32x4){0.f, 0.f, 0.f, 0.f};
    #pragma unroll
    for (int kt = 0; kt < 4; kt++) {
        bf16x8 a = *(const bf16x8*)&sA[(r0 + l15) * 136 + kt * 32 + quad * 8];
        #pragma unroll
        for (int nt = 0; nt < 8; nt++) {
            bf16x8 b = *(const bf16x8*)&sW[(nt * 16 + l15) * 136 + kt * 32 + quad * 8];
            acc[nt] = __builtin_amdgcn_mfma_f32_16x16x32_bf16(a, b, acc[nt], 0, 0, 0);
        }
    }
    __syncthreads();
    #pragma unroll
    for (int nt = 0; nt < 8; nt++)
        #pragma unroll
        for (int reg = 0; reg < 4; reg++)
            sOut[(r0 + quad * 4 + reg) * 132 + nt * 16 + l15] = acc[nt][reg];
    __syncthreads();
    int c = tid & 127;
    int rbeg = (tid >> 7) * 32;
    float eb = ebL[c];
    float s = 0.f;
    int cur = sDst[rbeg];
    for (int r = rbeg; r < rbeg + 32; r++) {
        int d = sDst[r];
        if (d != cur) { atomicAdd(&agg[(size_t)cur * DDIM + c], s); s = 0.f; cur = d; }
        float v = sOut[r * 132 + c] + eb + h[(size_t)sSrc[r] * DDIM + c];
        s += fmaxf(v, 0.f);
    }
    atomicAdd(&agg[(size_t)cur * DDIM + c], s);
}

// ---------------- GEMM1 fused with z-computation and BN1 stats ----------------
__global__ __launch_bounds__(256) void k_gemm1z(const float* __restrict__ h,
                                                const float* __restrict__ agg,
                                                const float* __restrict__ epsP, int l,
                                                const short* __restrict__ W1tL,
                                                float* __restrict__ zz,
                                                float* __restrict__ stats) {
    __shared__ __align__(16) short sB[256 * 136];  // 69632 B
    __shared__ __align__(16) short sA[64 * 136];   // 17408 B
    int tid = threadIdx.x;
    int tile = blockIdx.x;
    float e1 = 1.f + epsP[l];
    const uint2* bg = (const uint2*)W1tL;
    #pragma unroll
    for (int i = 0; i < 32; i++) {
        int idx = tid + i * 256;
        uint2 v = bg[idx];
        int n = idx >> 5, k4 = (idx & 31) << 2;
        *(uint2*)&sB[n * 136 + k4] = v;
    }
    #pragma unroll
    for (int i = 0; i < 8; i++) {
        int idx = tid + i * 256;           // 0..2047 float4 units (64 rows x 32)
        int r = idx >> 5, c4 = idx & 31;
        int gr = tile * 64 + r;
        short4 o = {0, 0, 0, 0};
        if (gr < NN) {
            float4 hv = ((const float4*)h)[gr * 32 + c4];
            float4 av = ((const float4*)agg)[gr * 32 + c4];
            o.x = f2bf(e1 * hv.x + av.x);
            o.y = f2bf(e1 * hv.y + av.y);
            o.z = f2bf(e1 * hv.z + av.z);
            o.w = f2bf(e1 * hv.w + av.w);
        }
        *(short4*)&sA[r * 136 + (c4 << 2)] = o;
    }
    __syncthreads();
    int lane = tid & 63, wv = tid >> 6;
    int l15 = lane & 15, quad = lane >> 4;
    int r0 = wv * 16;
    f32x4 acc[16];
    #pragma unroll
    for (int i = 0; i < 16; i++) acc[i] = (f32x4){0.f, 0.f, 0.f, 0.f};
    #pragma unroll
    for (int kt = 0; kt < 4; kt++) {
        bf16x8 a = *(const bf16x8*)&sA[(r0 + l15) * 136 + kt * 32 + quad * 8];
        #pragma unroll
        for (int nt = 0; nt < 16; nt++) {
            bf16x8 b = *(const bf16x8*)&sB[(nt * 16 + l15) * 136 + kt * 32 + quad * 8];
            acc[nt] = __builtin_amdgcn_mfma_f32_16x16x32_bf16(a, b, acc[nt], 0, 0, 0);
        }
    }
    int grb = tile * 64 + r0 + quad * 4;
    #pragma unroll
    for (int nt = 0; nt < 16; nt++) {
        float s = 0.f, s2 = 0.f;
        #pragma unroll
        for (int reg = 0; reg < 4; reg++) {
            int gr = grb + reg;
            float v = acc[nt][reg];
            s += v; s2 += v * v;
            if (gr < NN) zz[(size_t)gr * D2 + nt * 16 + l15] = v;
        }
        s += __shfl_xor(s, 16);  s += __shfl_xor(s, 32);
        s2 += __shfl_xor(s2, 16); s2 += __shfl_xor(s2, 32);
        if (quad == 0) {
            atomicAdd(&stats[nt * 16 + l15], s);
            atomicAdd(&stats[D2 + nt * 16 + l15], s2);
        }
    }
}

__global__ void k_finalize(const float* __restrict__ sums,
                           const float* __restrict__ g, const float* __restrict__ beta,
                           float* __restrict__ scale, float* __restrict__ shift, int ncols) {
    int c = threadIdx.x;
    float inv_n = 1.f / (float)NN;
    float mu = sums[c] * inv_n;
    float var = sums[ncols + c] * inv_n - mu * mu;
    float sc = g[c] * rsqrtf(var + BN_EPS);
    scale[c] = sc;
    shift[c] = beta[c] - mu * sc;
}

// ---------------- GEMM2 fused with BN2 stats ----------------
__global__ __launch_bounds__(256) void k_gemm2s(const float* __restrict__ zz,
                                                const short* __restrict__ W2tL,
                                                const float* __restrict__ scale1,
                                                const float* __restrict__ shift1,
                                                float* __restrict__ h_pre,
                                                float* __restrict__ stats) {
    __shared__ __align__(16) short sB[128 * 264];   // 67584 B
    __shared__ __align__(16) short sA[64 * 264];    // 33792 B
    __shared__ float sSc[256], sSh[256];
    int tid = threadIdx.x;
    int tile = blockIdx.x;
    sSc[tid] = scale1[tid];
    sSh[tid] = shift1[tid];
    const uint2* bg = (const uint2*)W2tL;
    #pragma unroll
    for (int i = 0; i < 32; i++) {
        int idx = tid + i * 256;
        uint2 v = bg[idx];
        int n = idx >> 6, k4 = (idx & 63) << 2;
        *(uint2*)&sB[n * 264 + k4] = v;
    }
    __syncthreads();
    #pragma unroll
    for (int i = 0; i < 16; i++) {
        int idx = tid + i * 256;           // 0..4095 float4 units (64 x 64)
        int r = idx >> 6, c4q = idx & 63;
        int c4 = c4q << 2;
        int gr = tile * 64 + r;
        short4 o = {0, 0, 0, 0};
        if (gr < NN) {
            float4 v = ((const float4*)zz)[gr * 64 + c4q];
            o.x = f2bf(fmaxf(v.x * sSc[c4 + 0] + sSh[c4 + 0], 0.f));
            o.y = f2bf(fmaxf(v.y * sSc[c4 + 1] + sSh[c4 + 1], 0.f));
            o.z = f2bf(fmaxf(v.z * sSc[c4 + 2] + sSh[c4 + 2], 0.f));
            o.w = f2bf(fmaxf(v.w * sSc[c4 + 3] + sSh[c4 + 3], 0.f));
        }
        *(short4*)&sA[r * 264 + c4] = o;
    }
    __syncthreads();
    int lane = tid & 63, wv = tid >> 6;
    int l15 = lane & 15, quad = lane >> 4;
    int r0 = wv * 16;
    f32x4 acc[8];
    #pragma unroll
    for (int i = 0; i < 8; i++) acc[i] = (f32x4){0.f, 0.f, 0.f, 0.f};
    #pragma unroll
    for (int kt = 0; kt < 8; kt++) {
        bf16x8 a = *(const bf16x8*)&sA[(r0 + l15) * 264 + kt * 32 + quad * 8];
        #pragma unroll
        for (int nt = 0; nt < 8; nt++) {
            bf16x8 b = *(const bf16x8*)&sB[(nt * 16 + l15) * 264 + kt * 32 + quad * 8];
            acc[nt] = __builtin_amdgcn_mfma_f32_16x16x32_bf16(a, b, acc[nt], 0, 0, 0);
        }
    }
    int grb = tile * 64 + r0 + quad * 4;
    #pragma unroll
    for (int nt = 0; nt < 8; nt++) {
        float s = 0.f, s2 = 0.f;
        #pragma unroll
        for (int reg = 0; reg < 4; reg++) {
            int gr = grb + reg;
            float v = acc[nt][reg];
            s += v; s2 += v * v;
            if (gr < NN) h_pre[(size_t)gr * DDIM + nt * 16 + l15] = v;
        }
        s += __shfl_xor(s, 16);  s += __shfl_xor(s, 32);
        s2 += __shfl_xor(s2, 16); s2 += __shfl_xor(s2, 32);
        if (quad == 0) {
            atomicAdd(&stats[nt * 16 + l15], s);
            atomicAdd(&stats[DDIM + nt * 16 + l15], s2);
        }
    }
}

// ---------------- outer BN (+optional relu) ----------------
__global__ __launch_bounds__(256) void k_bn2(const float* __restrict__ h_pre,
                                             const float* __restrict__ scale2,
                                             const float* __restrict__ shift2,
                                             int do_relu, float* __restrict__ dst) {
    int gid = blockIdx.x * 256 + threadIdx.x;
    int c0 = (gid & 31) << 2;
    float4 v = ((const float4*)h_pre)[gid];
    float4 o;
    o.x = v.x * scale2[c0 + 0] + shift2[c0 + 0];
    o.y = v.y * scale2[c0 + 1] + shift2[c0 + 1];
    o.z = v.z * scale2[c0 + 2] + shift2[c0 + 2];
    o.w = v.w * scale2[c0 + 3] + shift2[c0 + 3];
    if (do_relu) {
        o.x = fmaxf(o.x, 0.f); o.y = fmaxf(o.y, 0.f);
        o.z = fmaxf(o.z, 0.f); o.w = fmaxf(o.w, 0.f);
    }
    ((float4*)dst)[gid] = o;
}

extern "C" void kernel_launch(void* const* d_in, const int* in_sizes, int n_in,
                              void* d_out, int out_size, void* d_ws, size_t ws_size,
                              hipStream_t stream) {
    const int*   tok       = (const int*)d_in[0];
    const int*   ei        = (const int*)d_in[1];
    const float* edge_attr = (const float*)d_in[2];
    const float* emb       = (const float*)d_in[3];
    const float* eeW       = (const float*)d_in[4];
    const float* eeB       = (const float*)d_in[5];
    const float* W1        = (const float*)d_in[6];
    const float* bn1g      = (const float*)d_in[8];
    const float* bn1b      = (const float*)d_in[9];
    const float* W2        = (const float*)d_in[10];
    const float* epsP      = (const float*)d_in[12];
    const float* bng       = (const float*)d_in[13];
    const float* bnb       = (const float*)d_in[14];
    float* out = (float*)d_out;

    char* ws = (char*)d_ws;
    size_t off = 0;
    auto alloc = [&](size_t bytes) -> char* {
        off = (off + 511) & ~(size_t)511;
        char* p = ws + off;
        off += bytes;
        return p;
    };
    float* h      = (float*)alloc((size_t)NN * DDIM * 4);
    float* agg    = (float*)alloc((size_t)NN * DDIM * 4);
    float* zz     = (float*)alloc((size_t)NN * D2 * 4);
    float* h_pre  = (float*)alloc((size_t)NN * DDIM * 4);
    int*   perm   = (int*)alloc((size_t)EE * 4);
    int*   counts = (int*)alloc((size_t)NN * 4);
    int*   cursor = (int*)alloc((size_t)NN * 4);
    int*   srcs   = (int*)alloc((size_t)EE * 4);
    int*   dsts   = (int*)alloc((size_t)EE * 4);
    short* WtE    = (short*)alloc((size_t)NLAY * 128 * 128 * 2);
    short* W1t    = (short*)alloc((size_t)NLAY * 128 * 256 * 2);
    short* W2t    = (short*)alloc((size_t)NLAY * 256 * 128 * 2);
    float* stats  = (float*)alloc(768 * 4);
    float* scale1 = (float*)alloc(256 * 4);
    float* shift1 = (float*)alloc(256 * 4);
    float* scale2 = (float*)alloc(128 * 4);
    float* shift2 = (float*)alloc(128 * 4);
    short* ea_bf  = (short*)alloc((size_t)EE * DDIM * 2);   // 164 MB, allocated last
    bool big = (off <= ws_size);
    (void)in_sizes; (void)n_in; (void)out_size;

    hipMemsetAsync(counts, 0, (size_t)NN * 4, stream);
    {
        int t1 = NLAY * 128 * 128;
        k_prepw<<<(t1 + 255) / 256, 256, 0, stream>>>(eeW, WtE, 128, 128, t1);
        int t2 = NLAY * 128 * 256;
        k_prepw<<<(t2 + 255) / 256, 256, 0, stream>>>(W1, W1t, 128, 256, t2);
        int t3 = NLAY * 256 * 128;
        k_prepw<<<(t3 + 255) / 256, 256, 0, stream>>>(W2, W2t, 256, 128, t3);
    }
    k_embed<<<2500, 256, 0, stream>>>(tok, emb, h);
    k_hist<<<2500, 256, 0, stream>>>(ei, counts);
    k_scan<<<1, 1024, 0, stream>>>(counts, cursor);
    k_scatter<<<2500, 256, 0, stream>>>(ei, cursor, perm);
    if (big) {
        k_permute<<<EE * 32 / 256, 256, 0, stream>>>(edge_attr, ei, perm, ea_bf, srcs, dsts);
    }

    for (int l = 0; l < NLAY; l++) {
        hipMemsetAsync(agg, 0, (size_t)NN * DDIM * 4, stream);
        hipMemsetAsync(stats, 0, 768 * 4, stream);
        if (big) {
            k_edge2<<<EE / 64, 256, 0, stream>>>(ea_bf, srcs, dsts,
                                                 WtE + (size_t)l * 128 * 128,
                                                 eeB + (size_t)l * 128, h, agg);
        } else {
            k_edge_g<<<EE / 64, 256, 0, stream>>>(edge_attr, WtE + (size_t)l * 128 * 128,
                                                  eeB + (size_t)l * 128, h, ei, perm, agg);
        }
        k_gemm1z<<<(NN + 63) / 64, 256, 0, stream>>>(h, agg, epsP, l,
                                                     W1t + (size_t)l * 128 * 256, zz, stats);
        k_finalize<<<1, 256, 0, stream>>>(stats, bn1g + (size_t)l * 256, bn1b + (size_t)l * 256,
                                          scale1, shift1, 256);
        k_gemm2s<<<(NN + 63) / 64, 256, 0, stream>>>(zz, W2t + (size_t)l * 256 * 128,
                                                     scale1, shift1, h_pre, stats + 512);
        k_finalize<<<1, 128, 0, stream>>>(stats + 512, bng + (size_t)l * 128, bnb + (size_t)l * 128,
                                          scale2, shift2, 128);
        k_bn2<<<2500, 256, 0, stream>>>(h_pre, scale2, shift2, (l < NLAY - 1) ? 1 : 0,
                                        (l == NLAY - 1) ? out : h);
    }
}

// Round 3
// 1284.616 us; speedup vs baseline: 1.3675x; 1.3675x over previous
//
#include <hip/hip_runtime.h>
#include <stdint.h>

#define NN 20000
#define EE 640000
#define DDIM 128
#define D2 256
#define NLAY 3
#define BN_EPS 1e-5f

typedef short bf16x8 __attribute__((ext_vector_type(8)));
typedef float f32x4 __attribute__((ext_vector_type(4)));

__device__ __forceinline__ short f2bf(float f) {
    uint32_t u = __float_as_uint(f);
    u += 0x7fff + ((u >> 16) & 1);   // round-to-nearest-even
    return (short)(u >> 16);
}
__device__ __forceinline__ float bf2f(uint32_t u16) {
    return __uint_as_float(u16 << 16);
}

// ---------------- embedding ----------------
__global__ __launch_bounds__(256) void k_embed(const int* __restrict__ tok,
                                               const float* __restrict__ emb,
                                               float* __restrict__ h) {
    int gid = blockIdx.x * 256 + threadIdx.x;
    int r = gid >> 5;
    int c4 = gid & 31;
    int t = tok[r];
    ((float4*)h)[gid] = ((const float4*)emb)[t * 32 + c4];
}

// ---------------- counting sort of edges by dst ----------------
__global__ __launch_bounds__(256) void k_hist(const int* __restrict__ ei, int* __restrict__ counts) {
    int e = blockIdx.x * 256 + threadIdx.x;
    atomicAdd(&counts[ei[EE + e]], 1);
}

__global__ __launch_bounds__(1024) void k_scan(const int* __restrict__ counts, int* __restrict__ cursor) {
    __shared__ int part[1024];
    int t = threadIdx.x;
    int base = t * 20;
    int s = 0;
    for (int i = 0; i < 20; i++) {
        int idx = base + i;
        if (idx < NN) s += counts[idx];
    }
    part[t] = s;
    __syncthreads();
    for (int off = 1; off < 1024; off <<= 1) {
        int v = (t >= off) ? part[t - off] : 0;
        __syncthreads();
        part[t] += v;
        __syncthreads();
    }
    int run = part[t] - s;
    for (int i = 0; i < 20; i++) {
        int idx = base + i;
        if (idx < NN) { cursor[idx] = run; run += counts[idx]; }
    }
}

__global__ __launch_bounds__(256) void k_scatter(const int* __restrict__ ei,
                                                 int* __restrict__ cursor,
                                                 int* __restrict__ perm,
                                                 int* __restrict__ rank) {
    int e = blockIdx.x * 256 + threadIdx.x;
    int d = ei[EE + e];
    int pos = atomicAdd(&cursor[d], 1);
    perm[pos] = e;
    rank[e] = pos;
}

// ---------------- permute edge_attr into sorted order + bf16 (coalesced read, scattered write) ----
__global__ __launch_bounds__(256) void k_permute2(const float* __restrict__ edge_attr,
                                                  const int* __restrict__ ei,
                                                  const int* __restrict__ rank,
                                                  short* __restrict__ ea_bf,
                                                  int* __restrict__ srcs,
                                                  int* __restrict__ dsts) {
    int gid = blockIdx.x * 256 + threadIdx.x;   // 0..EE*32-1
    int e = gid >> 5, c4 = gid & 31;
    float4 v = ((const float4*)edge_attr)[gid];
    int pos = rank[e];
    short4 b;
    b.x = f2bf(v.x); b.y = f2bf(v.y); b.z = f2bf(v.z); b.w = f2bf(v.w);
    ((short4*)ea_bf)[(size_t)pos * 32 + c4] = b;
    if (c4 == 0) { srcs[pos] = ei[e]; dsts[pos] = ei[EE + e]; }
}

// ---------------- weight prep: transpose + fp32->bf16 ----------------
__global__ __launch_bounds__(256) void k_prepw(const float* __restrict__ src,
                                               short* __restrict__ dst,
                                               int K, int Nc, int total) {
    int gid = blockIdx.x * 256 + threadIdx.x;
    if (gid >= total) return;
    int per = K * Nc;
    int l = gid / per;
    int rem = gid - l * per;
    int k = rem / Nc;
    int n = rem - k * Nc;
    dst[(l * Nc + n) * K + k] = f2bf(src[gid]);
}

// ---------------- fused edge kernel (sorted bf16, parallel gather, lazy BN on h) ----------------
__global__ __launch_bounds__(256) void k_edge3(const short* __restrict__ ea_bf,
                                               const int* __restrict__ srcs,
                                               const int* __restrict__ dsts,
                                               const short* __restrict__ WtL,
                                               const float* __restrict__ ebL,
                                               const float* __restrict__ hbase,
                                               const float* __restrict__ sc2,
                                               const float* __restrict__ sh2,
                                               int lazy,
                                               float* __restrict__ agg) {
    __shared__ __align__(16) short sW[128 * 136];      // 34816 B
    __shared__ __align__(16) short sOutB[64 * 132];    // 16896 B (bf16 msg tile)
    __shared__ int sSrc[64], sDst[64];
    int tid = threadIdx.x;
    int tile = blockIdx.x;

    if (tid < 64) {
        sSrc[tid] = srcs[tile * 64 + tid];
        sDst[tid] = dsts[tile * 64 + tid];
    }
    // stage W (16384 bf16 = 4096 uint2)
    const uint2* wg = (const uint2*)WtL;
    #pragma unroll
    for (int i = 0; i < 16; i++) {
        int idx = tid + i * 256;
        uint2 v = wg[idx];
        int n = idx >> 5, k4 = (idx & 31) << 2;
        *(uint2*)&sW[n * 136 + k4] = v;
    }
    int lane = tid & 63, wv = tid >> 6;
    int l15 = lane & 15, quad = lane >> 4;
    int r0 = wv * 16;
    // A fragments straight from global (contiguous bf16 rows)
    const short* abase = ea_bf + ((size_t)(tile * 64 + r0 + l15)) * 128 + quad * 8;
    bf16x8 a[4];
    #pragma unroll
    for (int kt = 0; kt < 4; kt++) a[kt] = *(const bf16x8*)(abase + kt * 32);
    __syncthreads();   // sW + sSrc/sDst ready

    f32x4 acc[8];
    #pragma unroll
    for (int i = 0; i < 8; i++) acc[i] = (f32x4){0.f, 0.f, 0.f, 0.f};
    #pragma unroll
    for (int kt = 0; kt < 4; kt++) {
        #pragma unroll
        for (int nt = 0; nt < 8; nt++) {
            bf16x8 b = *(const bf16x8*)&sW[(nt * 16 + l15) * 136 + kt * 32 + quad * 8];
            acc[nt] = __builtin_amdgcn_mfma_f32_16x16x32_bf16(a[kt], b, acc[nt], 0, 0, 0);
        }
    }
    #pragma unroll
    for (int nt = 0; nt < 8; nt++)
        #pragma unroll
        for (int reg = 0; reg < 4; reg++)
            sOutB[(r0 + quad * 4 + reg) * 132 + nt * 16 + l15] = f2bf(acc[nt][reg]);
    __syncthreads();

    // parallel phase: msg = relu(geam + eb + BN2'(h[src])) — 16 independent iterations
    {
        int c2 = tid & 63;          // float2 column index (constant per thread)
        int c = c2 * 2;
        int rb = tid >> 6;          // 0..3
        float eb0 = ebL[c], eb1 = ebL[c + 1];
        float s0 = 0.f, s1 = 0.f, t0 = 0.f, t1 = 0.f;
        if (lazy) { s0 = sc2[c]; s1 = sc2[c + 1]; t0 = sh2[c]; t1 = sh2[c + 1]; }
        #pragma unroll
        for (int i = 0; i < 16; i++) {
            int r = rb + i * 4;
            float2 hv = *(const float2*)&hbase[(size_t)sSrc[r] * DDIM + c];
            float h0, h1;
            if (lazy) {
                h0 = fmaxf(hv.x * s0 + t0, 0.f);
                h1 = fmaxf(hv.y * s1 + t1, 0.f);
            } else {
                h0 = hv.x; h1 = hv.y;
            }
            uint32_t pp = *(uint32_t*)&sOutB[r * 132 + c];
            float m0 = fmaxf(bf2f(pp & 0xffffu) + eb0 + h0, 0.f);
            float m1 = fmaxf(bf2f(pp >> 16) + eb1 + h1, 0.f);
            uint32_t po = (uint32_t)(uint16_t)f2bf(m0) | ((uint32_t)(uint16_t)f2bf(m1) << 16);
            *(uint32_t*)&sOutB[r * 132 + c] = po;
        }
    }
    __syncthreads();
    // serial segmented reduce over LDS only
    int c = tid & 127;
    int rbeg = (tid >> 7) * 32;
    float s = 0.f;
    int cur = sDst[rbeg];
    for (int r = rbeg; r < rbeg + 32; r++) {
        int d = sDst[r];
        if (d != cur) { atomicAdd(&agg[(size_t)cur * DDIM + c], s); s = 0.f; cur = d; }
        uint32_t raw = *(const uint16_t*)&sOutB[r * 132 + c];
        s += bf2f(raw);
    }
    atomicAdd(&agg[(size_t)cur * DDIM + c], s);
}

// ---------------- fallback edge kernel (gather, no lazy BN) ----------------
__global__ __launch_bounds__(256) void k_edge_g(const float* __restrict__ edge_attr,
                                                const short* __restrict__ WtL,
                                                const float* __restrict__ ebL,
                                                const float* __restrict__ h,
                                                const int* __restrict__ ei,
                                                const int* __restrict__ perm,
                                                float* __restrict__ agg) {
    __shared__ __align__(16) short sW[128 * 136];
    __shared__ __align__(16) char sU[64 * 132 * 4];
    __shared__ int sSrc[64], sDst[64], sEdge[64];
    short* sA = (short*)sU;
    float* sOut = (float*)sU;
    int tid = threadIdx.x;
    int tile = blockIdx.x;
    if (tid < 64) {
        int e = perm[tile * 64 + tid];
        sEdge[tid] = e;
        sSrc[tid] = ei[e];
        sDst[tid] = ei[EE + e];
    }
    const uint2* wg = (const uint2*)WtL;
    #pragma unroll
    for (int i = 0; i < 16; i++) {
        int idx = tid + i * 256;
        uint2 v = wg[idx];
        int n = idx >> 5, k4 = (idx & 31) << 2;
        *(uint2*)&sW[n * 136 + k4] = v;
    }
    __syncthreads();
    #pragma unroll
    for (int i = 0; i < 8; i++) {
        int idx = tid + i * 256;
        int r = idx >> 5, c4 = idx & 31;
        float4 v = ((const float4*)edge_attr)[sEdge[r] * 32 + c4];
        short4 b;
        b.x = f2bf(v.x); b.y = f2bf(v.y); b.z = f2bf(v.z); b.w = f2bf(v.w);
        *(short4*)&sA[r * 136 + (c4 << 2)] = b;
    }
    __syncthreads();
    int lane = tid & 63, wv = tid >> 6;
    int l15 = lane & 15, quad = lane >> 4;
    int r0 = wv * 16;
    f32x4 acc[8];
    #pragma unroll
    for (int i = 0; i < 8; i++) acc[i] = (f32x4){0.f, 0.f, 0.f, 0.f};
    #pragma unroll
    for (int kt = 0; kt < 4; kt++) {
        bf16x8 a = *(const bf16x8*)&sA[(r0 + l15) * 136 + kt * 32 + quad * 8];
        #pragma unroll
        for (int nt = 0; nt < 8; nt++) {
            bf16x8 b = *(const bf16x8*)&sW[(nt * 16 + l15) * 136 + kt * 32 + quad * 8];
            acc[nt] = __builtin_amdgcn_mfma_f32_16x16x32_bf16(a, b, acc[nt], 0, 0, 0);
        }
    }
    __syncthreads();
    #pragma unroll
    for (int nt = 0; nt < 8; nt++)
        #pragma unroll
        for (int reg = 0; reg < 4; reg++)
            sOut[(r0 + quad * 4 + reg) * 132 + nt * 16 + l15] = acc[nt][reg];
    __syncthreads();
    #pragma unroll
    for (int i = 0; i < 32; i++) {
        int idx = tid + i * 256;
        int r = idx >> 7, c = idx & 127;
        float v = sOut[r * 132 + c] + ebL[c] + h[(size_t)sSrc[r] * DDIM + c];
        sOut[r * 132 + c] = fmaxf(v, 0.f);
    }
    __syncthreads();
    int c = tid & 127;
    int rbeg = (tid >> 7) * 32;
    float s = 0.f;
    int cur = sDst[rbeg];
    for (int r = rbeg; r < rbeg + 32; r++) {
        int d = sDst[r];
        if (d != cur) { atomicAdd(&agg[(size_t)cur * DDIM + c], s); s = 0.f; cur = d; }
        s += sOut[r * 132 + c];
    }
    atomicAdd(&agg[(size_t)cur * DDIM + c], s);
}

// ---------------- GEMM1 fused with z-computation, lazy BN2 on h, and BN1 stats ----------------
__global__ __launch_bounds__(256) void k_gemm1z(const float* __restrict__ hbase,
                                                const float* __restrict__ sc2,
                                                const float* __restrict__ sh2,
                                                int lazy,
                                                const float* __restrict__ agg,
                                                const float* __restrict__ epsP, int l,
                                                const short* __restrict__ W1tL,
                                                float* __restrict__ zz,
                                                float* __restrict__ stats) {
    __shared__ __align__(16) short sB[256 * 136];  // 69632 B
    __shared__ __align__(16) short sA[64 * 136];   // 17408 B
    int tid = threadIdx.x;
    int tile = blockIdx.x;
    float e1 = 1.f + epsP[l];
    const uint2* bg = (const uint2*)W1tL;
    #pragma unroll
    for (int i = 0; i < 32; i++) {
        int idx = tid + i * 256;
        uint2 v = bg[idx];
        int n = idx >> 5, k4 = (idx & 31) << 2;
        *(uint2*)&sB[n * 136 + k4] = v;
    }
    {
        int c4 = tid & 31;                 // constant per thread
        int c = c4 * 4;
        float4 sc = make_float4(0.f, 0.f, 0.f, 0.f), sh = make_float4(0.f, 0.f, 0.f, 0.f);
        if (lazy) {
            sc = *(const float4*)&sc2[c];
            sh = *(const float4*)&sh2[c];
        }
        #pragma unroll
        for (int i = 0; i < 8; i++) {
            int idx = tid + i * 256;       // r = idx>>5 in 0..63
            int r = idx >> 5;
            int gr = tile * 64 + r;
            short4 o = {0, 0, 0, 0};
            if (gr < NN) {
                float4 hv = ((const float4*)hbase)[gr * 32 + c4];
                if (lazy) {
                    hv.x = fmaxf(hv.x * sc.x + sh.x, 0.f);
                    hv.y = fmaxf(hv.y * sc.y + sh.y, 0.f);
                    hv.z = fmaxf(hv.z * sc.z + sh.z, 0.f);
                    hv.w = fmaxf(hv.w * sc.w + sh.w, 0.f);
                }
                float4 av = ((const float4*)agg)[gr * 32 + c4];
                o.x = f2bf(e1 * hv.x + av.x);
                o.y = f2bf(e1 * hv.y + av.y);
                o.z = f2bf(e1 * hv.z + av.z);
                o.w = f2bf(e1 * hv.w + av.w);
            }
            *(short4*)&sA[r * 136 + c] = o;
        }
    }
    __syncthreads();
    int lane = tid & 63, wv = tid >> 6;
    int l15 = lane & 15, quad = lane >> 4;
    int r0 = wv * 16;
    f32x4 acc[16];
    #pragma unroll
    for (int i = 0; i < 16; i++) acc[i] = (f32x4){0.f, 0.f, 0.f, 0.f};
    #pragma unroll
    for (int kt = 0; kt < 4; kt++) {
        bf16x8 a = *(const bf16x8*)&sA[(r0 + l15) * 136 + kt * 32 + quad * 8];
        #pragma unroll
        for (int nt = 0; nt < 16; nt++) {
            bf16x8 b = *(const bf16x8*)&sB[(nt * 16 + l15) * 136 + kt * 32 + quad * 8];
            acc[nt] = __builtin_amdgcn_mfma_f32_16x16x32_bf16(a, b, acc[nt], 0, 0, 0);
        }
    }
    int grb = tile * 64 + r0 + quad * 4;
    #pragma unroll
    for (int nt = 0; nt < 16; nt++) {
        float s = 0.f, s2 = 0.f;
        #pragma unroll
        for (int reg = 0; reg < 4; reg++) {
            int gr = grb + reg;
            float v = acc[nt][reg];
            s += v; s2 += v * v;
            if (gr < NN) zz[(size_t)gr * D2 + nt * 16 + l15] = v;
        }
        s += __shfl_xor(s, 16);  s += __shfl_xor(s, 32);
        s2 += __shfl_xor(s2, 16); s2 += __shfl_xor(s2, 32);
        if (quad == 0) {
            atomicAdd(&stats[nt * 16 + l15], s);
            atomicAdd(&stats[D2 + nt * 16 + l15], s2);
        }
    }
}

__global__ void k_finalize(const float* __restrict__ sums,
                           const float* __restrict__ g, const float* __restrict__ beta,
                           float* __restrict__ scale, float* __restrict__ shift, int ncols) {
    int c = threadIdx.x;
    float inv_n = 1.f / (float)NN;
    float mu = sums[c] * inv_n;
    float var = sums[ncols + c] * inv_n - mu * mu;
    float sc = g[c] * rsqrtf(var + BN_EPS);
    scale[c] = sc;
    shift[c] = beta[c] - mu * sc;
}

// ---------------- GEMM2 fused with BN2 stats ----------------
__global__ __launch_bounds__(256) void k_gemm2s(const float* __restrict__ zz,
                                                const short* __restrict__ W2tL,
                                                const float* __restrict__ scale1,
                                                const float* __restrict__ shift1,
                                                float* __restrict__ h_pre,
                                                float* __restrict__ stats) {
    __shared__ __align__(16) short sB[128 * 264];   // 67584 B
    __shared__ __align__(16) short sA[64 * 264];    // 33792 B
    __shared__ float sSc[256], sSh[256];
    int tid = threadIdx.x;
    int tile = blockIdx.x;
    sSc[tid] = scale1[tid];
    sSh[tid] = shift1[tid];
    const uint2* bg = (const uint2*)W2tL;
    #pragma unroll
    for (int i = 0; i < 32; i++) {
        int idx = tid + i * 256;
        uint2 v = bg[idx];
        int n = idx >> 6, k4 = (idx & 63) << 2;
        *(uint2*)&sB[n * 264 + k4] = v;
    }
    __syncthreads();
    #pragma unroll
    for (int i = 0; i < 16; i++) {
        int idx = tid + i * 256;
        int r = idx >> 6, c4q = idx & 63;
        int c4 = c4q << 2;
        int gr = tile * 64 + r;
        short4 o = {0, 0, 0, 0};
        if (gr < NN) {
            float4 v = ((const float4*)zz)[gr * 64 + c4q];
            o.x = f2bf(fmaxf(v.x * sSc[c4 + 0] + sSh[c4 + 0], 0.f));
            o.y = f2bf(fmaxf(v.y * sSc[c4 + 1] + sSh[c4 + 1], 0.f));
            o.z = f2bf(fmaxf(v.z * sSc[c4 + 2] + sSh[c4 + 2], 0.f));
            o.w = f2bf(fmaxf(v.w * sSc[c4 + 3] + sSh[c4 + 3], 0.f));
        }
        *(short4*)&sA[r * 264 + c4] = o;
    }
    __syncthreads();
    int lane = tid & 63, wv = tid >> 6;
    int l15 = lane & 15, quad = lane >> 4;
    int r0 = wv * 16;
    f32x4 acc[8];
    #pragma unroll
    for (int i = 0; i < 8; i++) acc[i] = (f32x4){0.f, 0.f, 0.f, 0.f};
    #pragma unroll
    for (int kt = 0; kt < 8; kt++) {
        bf16x8 a = *(const bf16x8*)&sA[(r0 + l15) * 264 + kt * 32 + quad * 8];
        #pragma unroll
        for (int nt = 0; nt < 8; nt++) {
            bf16x8 b = *(const bf16x8*)&sB[(nt * 16 + l15) * 264 + kt * 32 + quad * 8];
            acc[nt] = __builtin_amdgcn_mfma_f32_16x16x32_bf16(a, b, acc[nt], 0, 0, 0);
        }
    }
    int grb = tile * 64 + r0 + quad * 4;
    #pragma unroll
    for (int nt = 0; nt < 8; nt++) {
        float s = 0.f, s2 = 0.f;
        #pragma unroll
        for (int reg = 0; reg < 4; reg++) {
            int gr = grb + reg;
            float v = acc[nt][reg];
            s += v; s2 += v * v;
            if (gr < NN) h_pre[(size_t)gr * DDIM + nt * 16 + l15] = v;
        }
        s += __shfl_xor(s, 16);  s += __shfl_xor(s, 32);
        s2 += __shfl_xor(s2, 16); s2 += __shfl_xor(s2, 32);
        if (quad == 0) {
            atomicAdd(&stats[nt * 16 + l15], s);
            atomicAdd(&stats[DDIM + nt * 16 + l15], s2);
        }
    }
}

// ---------------- outer BN (+optional relu) ----------------
__global__ __launch_bounds__(256) void k_bn2(const float* __restrict__ h_pre,
                                             const float* __restrict__ scale2,
                                             const float* __restrict__ shift2,
                                             int do_relu, float* __restrict__ dst) {
    int gid = blockIdx.x * 256 + threadIdx.x;
    int c0 = (gid & 31) << 2;
    float4 v = ((const float4*)h_pre)[gid];
    float4 o;
    o.x = v.x * scale2[c0 + 0] + shift2[c0 + 0];
    o.y = v.y * scale2[c0 + 1] + shift2[c0 + 1];
    o.z = v.z * scale2[c0 + 2] + shift2[c0 + 2];
    o.w = v.w * scale2[c0 + 3] + shift2[c0 + 3];
    if (do_relu) {
        o.x = fmaxf(o.x, 0.f); o.y = fmaxf(o.y, 0.f);
        o.z = fmaxf(o.z, 0.f); o.w = fmaxf(o.w, 0.f);
    }
    ((float4*)dst)[gid] = o;
}

extern "C" void kernel_launch(void* const* d_in, const int* in_sizes, int n_in,
                              void* d_out, int out_size, void* d_ws, size_t ws_size,
                              hipStream_t stream) {
    const int*   tok       = (const int*)d_in[0];
    const int*   ei        = (const int*)d_in[1];
    const float* edge_attr = (const float*)d_in[2];
    const float* emb       = (const float*)d_in[3];
    const float* eeW       = (const float*)d_in[4];
    const float* eeB       = (const float*)d_in[5];
    const float* W1        = (const float*)d_in[6];
    const float* bn1g      = (const float*)d_in[8];
    const float* bn1b      = (const float*)d_in[9];
    const float* W2        = (const float*)d_in[10];
    const float* epsP      = (const float*)d_in[12];
    const float* bng       = (const float*)d_in[13];
    const float* bnb       = (const float*)d_in[14];
    float* out = (float*)d_out;

    char* ws = (char*)d_ws;
    size_t off = 0;
    auto alloc = [&](size_t bytes) -> char* {
        off = (off + 511) & ~(size_t)511;
        char* p = ws + off;
        off += bytes;
        return p;
    };
    float* h      = (float*)alloc((size_t)NN * DDIM * 4);
    float* agg    = (float*)alloc((size_t)NN * DDIM * 4);
    float* zz     = (float*)alloc((size_t)NN * D2 * 4);
    float* h_pre  = (float*)alloc((size_t)NN * DDIM * 4);
    int*   perm   = (int*)alloc((size_t)EE * 4);
    int*   rank   = (int*)alloc((size_t)EE * 4);
    int*   counts = (int*)alloc((size_t)NN * 4);
    int*   cursor = (int*)alloc((size_t)NN * 4);
    int*   srcs   = (int*)alloc((size_t)EE * 4);
    int*   dsts   = (int*)alloc((size_t)EE * 4);
    short* WtE    = (short*)alloc((size_t)NLAY * 128 * 128 * 2);
    short* W1t    = (short*)alloc((size_t)NLAY * 128 * 256 * 2);
    short* W2t    = (short*)alloc((size_t)NLAY * 256 * 128 * 2);
    float* stats  = (float*)alloc(768 * 4);
    float* scale1 = (float*)alloc(256 * 4);
    float* shift1 = (float*)alloc(256 * 4);
    float* scale2 = (float*)alloc(128 * 4);
    float* shift2 = (float*)alloc(128 * 4);
    short* ea_bf  = (short*)alloc((size_t)EE * DDIM * 2);   // 164 MB, allocated last
    bool big = (off <= ws_size);
    (void)in_sizes; (void)n_in; (void)out_size;

    hipMemsetAsync(counts, 0, (size_t)NN * 4, stream);
    {
        int t1 = NLAY * 128 * 128;
        k_prepw<<<(t1 + 255) / 256, 256, 0, stream>>>(eeW, WtE, 128, 128, t1);
        int t2 = NLAY * 128 * 256;
        k_prepw<<<(t2 + 255) / 256, 256, 0, stream>>>(W1, W1t, 128, 256, t2);
        int t3 = NLAY * 256 * 128;
        k_prepw<<<(t3 + 255) / 256, 256, 0, stream>>>(W2, W2t, 256, 128, t3);
    }
    k_embed<<<2500, 256, 0, stream>>>(tok, emb, h);
    k_hist<<<2500, 256, 0, stream>>>(ei, counts);
    k_scan<<<1, 1024, 0, stream>>>(counts, cursor);
    k_scatter<<<2500, 256, 0, stream>>>(ei, cursor, perm, rank);
    if (big) {
        k_permute2<<<EE * 32 / 256, 256, 0, stream>>>(edge_attr, ei, rank, ea_bf, srcs, dsts);
    }

    for (int l = 0; l < NLAY; l++) {
        hipMemsetAsync(agg, 0, (size_t)NN * DDIM * 4, stream);
        hipMemsetAsync(stats, 0, 768 * 4, stream);
        int lazy = (big && l > 0) ? 1 : 0;
        const float* hb = lazy ? h_pre : h;
        if (big) {
            k_edge3<<<EE / 64, 256, 0, stream>>>(ea_bf, srcs, dsts,
                                                 WtE + (size_t)l * 128 * 128,
                                                 eeB + (size_t)l * 128,
                                                 hb, scale2, shift2, lazy, agg);
        } else {
            k_edge_g<<<EE / 64, 256, 0, stream>>>(edge_attr, WtE + (size_t)l * 128 * 128,
                                                  eeB + (size_t)l * 128, h, ei, perm, agg);
        }
        k_gemm1z<<<(NN + 63) / 64, 256, 0, stream>>>(hb, scale2, shift2, lazy, agg, epsP, l,
                                                     W1t + (size_t)l * 128 * 256, zz, stats);
        k_finalize<<<1, 256, 0, stream>>>(stats, bn1g + (size_t)l * 256, bn1b + (size_t)l * 256,
                                          scale1, shift1, 256);
        k_gemm2s<<<(NN + 63) / 64, 256, 0, stream>>>(zz, W2t + (size_t)l * 256 * 128,
                                                     scale1, shift1, h_pre, stats + 512);
        k_finalize<<<1, 128, 0, stream>>>(stats + 512, bng + (size_t)l * 128, bnb + (size_t)l * 128,
                                          scale2, shift2, 128);
        if (big) {
            if (l == NLAY - 1)
                k_bn2<<<2500, 256, 0, stream>>>(h_pre, scale2, shift2, 0, out);
        } else {
            k_bn2<<<2500, 256, 0, stream>>>(h_pre, scale2, shift2, (l < NLAY - 1) ? 1 : 0,
                                            (l == NLAY - 1) ? out : h);
        }
    }
}